// Round 11
// baseline (128.975 us; speedup 1.0000x reference)
//
#include <hip/hip_runtime.h>
#include <math.h>

#define Bb 8
#define Tt 1000
#define TPAD 1024
#define NHh 8
#define Dd 64

typedef short bf16x8 __attribute__((ext_vector_type(8)));
typedef float f32x4 __attribute__((ext_vector_type(4)));

#define QOFF (-0.3f)
#define QSTEP (0.6f / 256.0f)
#define QINV (256.0f / 0.6f)
// p = exp2(CQ * sad)  where score = -(1/8)*STEP*sad
#define CQ (-0.125f * 1.44269504088896341f * QSTEP)

__device__ __forceinline__ unsigned sad_u8(unsigned a, unsigned b, unsigned c) {
#if __has_builtin(__builtin_amdgcn_sad_u8)
    return __builtin_amdgcn_sad_u8(a, b, c);
#else
    unsigned d;
    asm("v_sad_u8 %0, %1, %2, %3" : "=v"(d) : "v"(a), "v"(b), "v"(c));
    return d;
#endif
}

__device__ __forceinline__ unsigned quant8(float v) {
    float t = (v - QOFF) * QINV + 0.5f;
    t = fminf(fmaxf(t, 0.0f), 255.0f);
    return (unsigned)(int)t;
}

__device__ __forceinline__ unsigned cvt_pk_bf16(float lo, float hi) {
    unsigned r;
    asm("v_cvt_pk_bf16_f32 %0, %1, %2" : "=v"(r) : "v"(lo), "v"(hi));
    return r;
}

__device__ __forceinline__ unsigned short f2bf(float v) {
    return (unsigned short)(cvt_pk_bf16(v, v) & 0xffffu);
}

__device__ __forceinline__ float bf2f(unsigned short u) {
    union { unsigned u; float f; } x; x.u = ((unsigned)u) << 16; return x.f;
}

__device__ __forceinline__ bf16x8 mkbf(unsigned u0, unsigned u1, unsigned u2, unsigned u3) {
    union { unsigned u[4]; bf16x8 v; } x;
    x.u[0] = u0; x.u[1] = u1; x.u[2] = u2; x.u[3] = u3;
    return x.v;
}

__device__ __forceinline__ bf16x8 bfc(uint4 q) {
    union { uint4 q; bf16x8 v; } x; x.q = q; return x.v;
}

// async global->LDS, 16B per lane, dest = wave-uniform base + lane*16
#define GLDS(gsrc, ldst) \
    __builtin_amdgcn_global_load_lds((const __attribute__((address_space(1))) unsigned*)(gsrc), \
                                     (__attribute__((address_space(3))) unsigned*)(ldst), 16, 0, 0)

// ---------------- Kernel A: prep (unchanged) ----------------
__global__ __launch_bounds__(256) void prep_kernel(
    const float* __restrict__ x, const float* __restrict__ wq,
    const float* __restrict__ wv, const float* __restrict__ wk,
    unsigned* __restrict__ qq8, unsigned* __restrict__ kq8,
    uint4* __restrict__ vfrag)
{
    __shared__ float xs[64][68];
    __shared__ float ws[64][65];
    __shared__ float vS[64][68];
    const int tid = threadIdx.x;
    const int st = blockIdx.x;
    const int cb = blockIdx.y;
    const int b  = blockIdx.z;
    const bool isQ = (cb < 8);
    const int h = isQ ? cb : (cb - 8);
    const float* W = isQ ? wq : wv;
    const int cBase = h * 64;
    const int bh = b * NHh + h;

#pragma unroll
    for (int i = 0; i < 4; ++i) {
        int f4 = tid + i * 256;
        int r = f4 >> 4, c4 = (f4 & 15) << 2;
        int row = st * 64 + r; if (row >= Tt) row = Tt - 1;
        *(float4*)&xs[r][c4] = *(const float4*)&x[((size_t)b * Tt + row) * 64 + c4];
    }
#pragma unroll
    for (int i = 0; i < 16; ++i) {
        int idx = tid + i * 256;
        int c = idx >> 6, k = idx & 63;
        ws[c][k] = W[(cBase + c) * 65 + k];
    }
    __syncthreads();

    const int rg = tid >> 4, cg = tid & 15;
    const int r0 = rg * 4, c0 = cg * 4;
    float acc[4][4];
#pragma unroll
    for (int j = 0; j < 4; ++j) {
        float bias = W[(cBase + c0 + j) * 65 + 64];
#pragma unroll
        for (int i = 0; i < 4; ++i) acc[i][j] = bias;
    }
    for (int k0 = 0; k0 < 64; k0 += 4) {
        float4 a[4];
#pragma unroll
        for (int i = 0; i < 4; ++i) a[i] = *(const float4*)&xs[r0 + i][k0];
#pragma unroll
        for (int j = 0; j < 4; ++j) {
            float b0 = ws[c0 + j][k0 + 0];
            float b1 = ws[c0 + j][k0 + 1];
            float b2 = ws[c0 + j][k0 + 2];
            float b3 = ws[c0 + j][k0 + 3];
#pragma unroll
            for (int i = 0; i < 4; ++i)
                acc[i][j] += a[i].x * b0 + a[i].y * b1 + a[i].z * b2 + a[i].w * b3;
        }
    }

    if (isQ) {
#pragma unroll
        for (int i = 0; i < 4; ++i) {
            int t = st * 64 + r0 + i;
            unsigned d = 0u;
            if (t < Tt)
                d = quant8(acc[i][0]) | (quant8(acc[i][1]) << 8) |
                    (quant8(acc[i][2]) << 16) | (quant8(acc[i][3]) << 24);
            qq8[((size_t)bh * TPAD + t) * 16 + cg] = d;
        }
        {
            const int r = tid >> 2, c4 = tid & 3;
            const int t = st * 64 + r;
            unsigned kd[4];
            if (t < Tt) {
#pragma unroll
                for (int dw = 0; dw < 4; ++dw) {
                    int w = c4 * 16 + dw * 4;
                    float4 wkv = *(const float4*)&wk[h * 64 + w];
                    kd[dw] = quant8(xs[r][w + 0] * wkv.x) |
                             (quant8(xs[r][w + 1] * wkv.y) << 8) |
                             (quant8(xs[r][w + 2] * wkv.z) << 16) |
                             (quant8(xs[r][w + 3] * wkv.w) << 24);
                }
            } else {
                kd[0] = kd[1] = kd[2] = kd[3] = 0u;
            }
            const int c4s = c4 ^ ((r >> 3) & 3);
            *(uint4*)&kq8[((size_t)bh * TPAD + t) * 16 + c4s * 4] =
                make_uint4(kd[0], kd[1], kd[2], kd[3]);
        }
    } else {
#pragma unroll
        for (int i = 0; i < 4; ++i) {
            float4 o; o.x = acc[i][0]; o.y = acc[i][1]; o.z = acc[i][2]; o.w = acc[i][3];
            *(float4*)&vS[r0 + i][c0] = o;
        }
        __syncthreads();
#pragma unroll
        for (int e2 = 0; e2 < 2; ++e2) {
            int ent = tid + e2 * 256;
            int kk = ent >> 8, rem = ent & 255, n = rem >> 6, lane = rem & 63;
            int ts = kk * 32 + ((lane >> 4) << 3);
            int w  = n * 16 + (lane & 15);
            unsigned o[4];
#pragma unroll
            for (int pr = 0; pr < 4; ++pr) {
                int t0 = st * 64 + ts + pr * 2;
                float lo = (t0 < Tt)     ? vS[ts + pr * 2][w]     : 0.0f;
                float hi = (t0 + 1 < Tt) ? vS[ts + pr * 2 + 1][w] : 0.0f;
                o[pr] = cvt_pk_bf16(lo, hi);
            }
            vfrag[(((size_t)bh * 16 + st) * 8 + (kk * 4 + n)) * 64 + lane] =
                make_uint4(o[0], o[1], o[2], o[3]);
        }
    }
}

// ---------------- Kernel B: attention, A=4 rows/lane, wave-private k staging ----------------
// Grid (16 qt, 8 h, 16 bz): b=bz>>1, half=bz&1. Block = 4 waves; wave w owns source tiles
// {half*8+2w, +1} and ALL 64 q-rows (4 rows/lane: m, m+16, m+32, m+48). k tiles staged via
// GLDS into a wave-PRIVATE 8KB LDS region (both tiles up-front, one vmcnt(0), NO barriers
// in the compute loop). Each ds_read_b128 now feeds 4 q-rows (LDS pipe halves vs r10).
// Cross-wave numerator/denominator reduce at the end via 2-round LDS tree (reuses staging).
__global__ __launch_bounds__(256) void attn_kernel(
    const unsigned* __restrict__ qq8, const unsigned* __restrict__ kq8,
    const uint4* __restrict__ vfrag,
    unsigned short* __restrict__ numbf, float* __restrict__ dsums)
{
    __shared__ uint4 smem[2048];       // 32 KB: wave w -> smem[w*512 .. w*512+511]
    __shared__ float dredx[4][4][16];  // [wave][rowset][m]

    const int tid = threadIdx.x;
    const int wv_ = tid >> 6;          // wave 0..3
    const int l   = tid & 63;
    const int g   = l >> 4;            // 0..3
    const int m   = l & 15;
    const int qt  = blockIdx.x;        // 0..15
    const int h   = blockIdx.y;
    const int bz  = blockIdx.z;        // 0..15
    const int b   = bz >> 1;
    const int half = bz & 1;
    const int bh  = b * NHh + h;
    const int tb  = half * 8 + wv_ * 2;   // wave's first tile

    // 4 q rows per lane: qt*64 + m + 16*r (16 dw each)
    unsigned qA[16], qB[16], qC[16], qD[16];
    {
        const uint4* qp = (const uint4*)qq8 + ((size_t)bh * TPAD + qt * 64 + m) * 4;
        *(uint4*)&qA[0] = qp[0];       *(uint4*)&qA[4] = qp[1];
        *(uint4*)&qA[8] = qp[2];       *(uint4*)&qA[12] = qp[3];
        *(uint4*)&qB[0] = qp[64];      *(uint4*)&qB[4] = qp[65];
        *(uint4*)&qB[8] = qp[66];      *(uint4*)&qB[12] = qp[67];
        *(uint4*)&qC[0] = qp[128];     *(uint4*)&qC[4] = qp[129];
        *(uint4*)&qC[8] = qp[130];     *(uint4*)&qC[12] = qp[131];
        *(uint4*)&qD[0] = qp[192];     *(uint4*)&qD[4] = qp[193];
        *(uint4*)&qD[8] = qp[194];     *(uint4*)&qD[12] = qp[195];
    }

    const uint4* kg = (const uint4*)kq8 + (size_t)bh * 4096;  // tile t at +t*256
    const uint4* vg = vfrag + (size_t)bh * 8192;              // tile t at +t*512

    uint4* kw = &smem[wv_ * 512];      // wave-private 8 KB (2 tiles)
    {
#pragma unroll
        for (int c = 0; c < 4; ++c) GLDS(kg + tb * 256 + c * 64 + l,       &kw[c * 64]);
#pragma unroll
        for (int c = 0; c < 4; ++c) GLDS(kg + (tb + 1) * 256 + c * 64 + l, &kw[256 + c * 64]);
    }
    asm volatile("s_waitcnt vmcnt(0)" ::: "memory");
    __builtin_amdgcn_sched_barrier(0);

    f32x4 accA[4], accB[4], accC[4], accD[4];
#pragma unroll
    for (int n = 0; n < 4; ++n) {
        accA[n] = (f32x4){0.f,0.f,0.f,0.f};
        accB[n] = accA[n]; accC[n] = accA[n]; accD[n] = accA[n];
    }
    float dsA = 0.f, dsB = 0.f, dsC = 0.f, dsD = 0.f;

#pragma unroll
    for (int ti = 0; ti < 2; ++ti) {
        const int t = tb + ti;
        const uint4* kbase = &kw[ti * 256];
        const uint4* vt = vg + (size_t)t * 512 + l;

#pragma unroll
        for (int kk = 0; kk < 2; ++kk) {
            // V fragments (global, per-lane distinct; latency hides under SADs)
            uint4 vf0 = vt[(kk * 4 + 0) * 64];
            uint4 vf1 = vt[(kk * 4 + 1) * 64];
            uint4 vf2 = vt[(kk * 4 + 2) * 64];
            uint4 vf3 = vt[(kk * 4 + 3) * 64];

            const bool maskall = (t == 15) && (kk == 1) && (g >= 1);
            unsigned waA[4], waB[4], waC[4], waD[4];
            float pvA, pvB, pvC, pvD;
#pragma unroll
            for (int e = 0; e < 8; ++e) {
                const uint4* kb = kbase + ((kk * 32 + (g << 3) + e) << 2);
                uint4 c0 = kb[0 ^ g], c1 = kb[1 ^ g], c2 = kb[2 ^ g], c3 = kb[3 ^ g];
                const unsigned* k0 = (const unsigned*)&c0;
                const unsigned* k1 = (const unsigned*)&c1;
                const unsigned* k2 = (const unsigned*)&c2;
                const unsigned* k3 = (const unsigned*)&c3;
                unsigned sA0 = 0u, sA1 = 0u, sB0 = 0u, sB1 = 0u;
                unsigned sC0 = 0u, sC1 = 0u, sD0 = 0u, sD1 = 0u;
#pragma unroll
                for (int w = 0; w < 4; ++w) {
                    sA0 = sad_u8(qA[w],     k0[w], sA0); sA1 = sad_u8(qA[4 + w], k1[w], sA1);
                    sB0 = sad_u8(qB[w],     k0[w], sB0); sB1 = sad_u8(qB[4 + w], k1[w], sB1);
                    sC0 = sad_u8(qC[w],     k0[w], sC0); sC1 = sad_u8(qC[4 + w], k1[w], sC1);
                    sD0 = sad_u8(qD[w],     k0[w], sD0); sD1 = sad_u8(qD[4 + w], k1[w], sD1);
                }
#pragma unroll
                for (int w = 0; w < 4; ++w) {
                    sA0 = sad_u8(qA[8 + w], k2[w], sA0); sA1 = sad_u8(qA[12 + w], k3[w], sA1);
                    sB0 = sad_u8(qB[8 + w], k2[w], sB0); sB1 = sad_u8(qB[12 + w], k3[w], sB1);
                    sC0 = sad_u8(qC[8 + w], k2[w], sC0); sC1 = sad_u8(qC[12 + w], k3[w], sC1);
                    sD0 = sad_u8(qD[8 + w], k2[w], sD0); sD1 = sad_u8(qD[12 + w], k3[w], sD1);
                }
                float pA = maskall ? 0.f : __builtin_amdgcn_exp2f(CQ * (float)(sA0 + sA1));
                float pB = maskall ? 0.f : __builtin_amdgcn_exp2f(CQ * (float)(sB0 + sB1));
                float pC = maskall ? 0.f : __builtin_amdgcn_exp2f(CQ * (float)(sC0 + sC1));
                float pD = maskall ? 0.f : __builtin_amdgcn_exp2f(CQ * (float)(sD0 + sD1));
                dsA += pA; dsB += pB; dsC += pC; dsD += pD;
                if (e & 1) {
                    waA[e >> 1] = cvt_pk_bf16(pvA, pA);
                    waB[e >> 1] = cvt_pk_bf16(pvB, pB);
                    waC[e >> 1] = cvt_pk_bf16(pvC, pC);
                    waD[e >> 1] = cvt_pk_bf16(pvD, pD);
                } else { pvA = pA; pvB = pB; pvC = pC; pvD = pD; }
            }
            bf16x8 AA = mkbf(waA[0], waA[1], waA[2], waA[3]);
            bf16x8 AB = mkbf(waB[0], waB[1], waB[2], waB[3]);
            bf16x8 AC = mkbf(waC[0], waC[1], waC[2], waC[3]);
            bf16x8 AD = mkbf(waD[0], waD[1], waD[2], waD[3]);

            accA[0] = __builtin_amdgcn_mfma_f32_16x16x32_bf16(AA, bfc(vf0), accA[0], 0, 0, 0);
            accB[0] = __builtin_amdgcn_mfma_f32_16x16x32_bf16(AB, bfc(vf0), accB[0], 0, 0, 0);
            accC[0] = __builtin_amdgcn_mfma_f32_16x16x32_bf16(AC, bfc(vf0), accC[0], 0, 0, 0);
            accD[0] = __builtin_amdgcn_mfma_f32_16x16x32_bf16(AD, bfc(vf0), accD[0], 0, 0, 0);
            accA[1] = __builtin_amdgcn_mfma_f32_16x16x32_bf16(AA, bfc(vf1), accA[1], 0, 0, 0);
            accB[1] = __builtin_amdgcn_mfma_f32_16x16x32_bf16(AB, bfc(vf1), accB[1], 0, 0, 0);
            accC[1] = __builtin_amdgcn_mfma_f32_16x16x32_bf16(AC, bfc(vf1), accC[1], 0, 0, 0);
            accD[1] = __builtin_amdgcn_mfma_f32_16x16x32_bf16(AD, bfc(vf1), accD[1], 0, 0, 0);
            accA[2] = __builtin_amdgcn_mfma_f32_16x16x32_bf16(AA, bfc(vf2), accA[2], 0, 0, 0);
            accB[2] = __builtin_amdgcn_mfma_f32_16x16x32_bf16(AB, bfc(vf2), accB[2], 0, 0, 0);
            accC[2] = __builtin_amdgcn_mfma_f32_16x16x32_bf16(AC, bfc(vf2), accC[2], 0, 0, 0);
            accD[2] = __builtin_amdgcn_mfma_f32_16x16x32_bf16(AD, bfc(vf2), accD[2], 0, 0, 0);
            accA[3] = __builtin_amdgcn_mfma_f32_16x16x32_bf16(AA, bfc(vf3), accA[3], 0, 0, 0);
            accB[3] = __builtin_amdgcn_mfma_f32_16x16x32_bf16(AB, bfc(vf3), accB[3], 0, 0, 0);
            accC[3] = __builtin_amdgcn_mfma_f32_16x16x32_bf16(AC, bfc(vf3), accC[3], 0, 0, 0);
            accD[3] = __builtin_amdgcn_mfma_f32_16x16x32_bf16(AD, bfc(vf3), accD[3], 0, 0, 0);
        }
    }

    // intra-wave denominator reduce over the 4 lane-groups sharing m
    dsA += __shfl_xor(dsA, 16); dsA += __shfl_xor(dsA, 32);
    dsB += __shfl_xor(dsB, 16); dsB += __shfl_xor(dsB, 32);
    dsC += __shfl_xor(dsC, 16); dsC += __shfl_xor(dsC, 32);
    dsD += __shfl_xor(dsD, 16); dsD += __shfl_xor(dsD, 32);

    __syncthreads();   // all waves finished reading their staging regions

    f32x4* red = (f32x4*)smem;   // 2048 f32x4 (reuses the 32 KB staging)
    if (l < 16) {
        dredx[wv_][0][l] = dsA; dredx[wv_][1][l] = dsB;
        dredx[wv_][2][l] = dsC; dredx[wv_][3][l] = dsD;
    }

#define PUB(SLOT) do { \
        _Pragma("unroll") for (int n = 0; n < 4; ++n) { \
            red[(SLOT) * 1024 + (0 * 4 + n) * 64 + l] = accA[n]; \
            red[(SLOT) * 1024 + (1 * 4 + n) * 64 + l] = accB[n]; \
            red[(SLOT) * 1024 + (2 * 4 + n) * 64 + l] = accC[n]; \
            red[(SLOT) * 1024 + (3 * 4 + n) * 64 + l] = accD[n]; \
        } } while (0)
#define ADD(SLOT) do { \
        _Pragma("unroll") for (int n = 0; n < 4; ++n) { \
            f32x4 ra = red[(SLOT) * 1024 + (0 * 4 + n) * 64 + l]; \
            f32x4 rb = red[(SLOT) * 1024 + (1 * 4 + n) * 64 + l]; \
            f32x4 rc = red[(SLOT) * 1024 + (2 * 4 + n) * 64 + l]; \
            f32x4 rd = red[(SLOT) * 1024 + (3 * 4 + n) * 64 + l]; \
            _Pragma("unroll") for (int j = 0; j < 4; ++j) { \
                accA[n][j] += ra[j]; accB[n][j] += rb[j]; \
                accC[n][j] += rc[j]; accD[n][j] += rd[j]; } \
        } } while (0)

    // round 1: waves 1,3 publish; waves 0,2 add
    if (wv_ & 1) PUB(wv_ >> 1);
    __syncthreads();
    if (!(wv_ & 1)) ADD(wv_ >> 1);
    __syncthreads();
    // round 2: wave 2 publishes; wave 0 adds and writes out
    if (wv_ == 2) PUB(0);
    __syncthreads();
    if (wv_ == 0) {
        ADD(0);
        float dT0 = dredx[0][0][m] + dredx[1][0][m] + dredx[2][0][m] + dredx[3][0][m];
        float dT1 = dredx[0][1][m] + dredx[1][1][m] + dredx[2][1][m] + dredx[3][1][m];
        float dT2 = dredx[0][2][m] + dredx[1][2][m] + dredx[2][2][m] + dredx[3][2][m];
        float dT3 = dredx[0][3][m] + dredx[1][3][m] + dredx[2][3][m] + dredx[3][3][m];

#define STOREROW(ACC, RS) do { \
        _Pragma("unroll") for (int j = 0; j < 4; ++j) { \
            int row = qt * 64 + (RS) * 16 + g * 4 + j; \
            if (row < Tt) { \
                unsigned short* o = numbf + (((size_t)(b * Tt + row) * 16) + h * 2 + half) * 64 + m; \
                o[0]  = f2bf(ACC[0][j]); \
                o[16] = f2bf(ACC[1][j]); \
                o[32] = f2bf(ACC[2][j]); \
                o[48] = f2bf(ACC[3][j]); \
            } } } while (0)
        STOREROW(accA, 0);
        STOREROW(accB, 1);
        STOREROW(accC, 2);
        STOREROW(accD, 3);
#undef STOREROW
        if (l < 16) {
            int r0_ = qt * 64 + m,      r1_ = qt * 64 + 16 + m;
            int r2_ = qt * 64 + 32 + m, r3_ = qt * 64 + 48 + m;
            if (r0_ < Tt) dsums[(((size_t)(b * Tt + r0_) * 8) + h) * 2 + half] = dT0;
            if (r1_ < Tt) dsums[(((size_t)(b * Tt + r1_) * 8) + h) * 2 + half] = dT1;
            if (r2_ < Tt) dsums[(((size_t)(b * Tt + r2_) * 8) + h) * 2 + half] = dT2;
            if (r3_ < Tt) dsums[(((size_t)(b * Tt + r3_) * 8) + h) * 2 + half] = dT3;
        }
    }
#undef PUB
#undef ADD
}

// ---------------- Kernel C: normalize + half/head-sum + ReLU + wf proj + residual ----
__global__ __launch_bounds__(256) void finalize_kernel(
    const float* __restrict__ x, const float* __restrict__ wf,
    const unsigned short* __restrict__ numbf, const float* __restrict__ dsums,
    float* __restrict__ out)
{
    __shared__ float wfs[64][65];
    __shared__ float osh[4][64];
    const int tid = threadIdx.x;
    for (int i = tid; i < 64 * 65; i += 256) wfs[i / 65][i % 65] = wf[i];
    const int wave = tid >> 6, lane = tid & 63;
    const int token = blockIdx.x * 4 + wave;   // 0..7999

    const float dsv = dsums[(size_t)token * 16 + (lane & 15)];
    const unsigned short* np = numbf + (size_t)token * 1024;
    float o = 0.f;
#pragma unroll
    for (int hh = 0; hh < 8; ++hh) {
        float den = 1.0f + __shfl(dsv, 2 * hh) + __shfl(dsv, 2 * hh + 1);
        float inv = 1.0f / den;
        float a0 = bf2f(np[(2 * hh) * 64 + lane]);
        float a1 = bf2f(np[(2 * hh + 1) * 64 + lane]);
        o += (a0 + a1) * inv;
    }
    o = fmaxf(o, 0.f);
    osh[wave][lane] = o;
    __syncthreads();
    float acc = wfs[lane][64];    // bias
#pragma unroll 8
    for (int w = 0; w < 64; ++w) acc += wfs[lane][w] * osh[wave][w];
    out[(size_t)token * Dd + lane] = x[(size_t)token * Dd + lane] + acc;
}

extern "C" void kernel_launch(void* const* d_in, const int* in_sizes, int n_in,
                              void* d_out, int out_size, void* d_ws, size_t ws_size,
                              hipStream_t stream)
{
    const float* x  = (const float*)d_in[0];
    const float* wq = (const float*)d_in[1];
    const float* wv = (const float*)d_in[2];
    const float* wk = (const float*)d_in[3];
    const float* wf = (const float*)d_in[4];
    float* out = (float*)d_out;

    char* base = (char*)d_ws;
    unsigned short* numbf = (unsigned short*)base;                    // 16,384,000 B
    float*    dsums = (float*)(base + 16384000);                      //    512,000 B
    unsigned* qq8   = (unsigned*)(base + 16896000);                   //  4,194,304 B
    unsigned* kq8   = (unsigned*)(base + 16896000 + 4194304);         //  4,194,304 B
    uint4*    vfrag = (uint4*)(base + 16896000 + 2 * 4194304);        //  8,388,608 B

    prep_kernel<<<dim3(16, 16, Bb), 256, 0, stream>>>(x, wq, wv, wk, qq8, kq8, vfrag);
    attn_kernel<<<dim3(16, NHh, 2 * Bb), 256, 0, stream>>>(qq8, kq8, vfrag, numbf, dsums);
    finalize_kernel<<<2000, 256, 0, stream>>>(x, wf, numbf, dsums, out);
}

// Round 12
// 97.899 us; speedup vs baseline: 1.3174x; 1.3174x over previous
//
#include <hip/hip_runtime.h>
#include <math.h>

#define Bb 8
#define Tt 1000
#define TPAD 1024
#define NHh 8
#define Dd 64

typedef short bf16x8 __attribute__((ext_vector_type(8)));
typedef float f32x4 __attribute__((ext_vector_type(4)));

#define QOFF (-0.3f)
#define QSTEP (0.6f / 256.0f)
#define QINV (256.0f / 0.6f)
// p = exp2(CQ * sad)  where score = -(1/8)*STEP*sad
#define CQ (-0.125f * 1.44269504088896341f * QSTEP)

__device__ __forceinline__ unsigned sad_u8(unsigned a, unsigned b, unsigned c) {
#if __has_builtin(__builtin_amdgcn_sad_u8)
    return __builtin_amdgcn_sad_u8(a, b, c);
#else
    unsigned d;
    asm("v_sad_u8 %0, %1, %2, %3" : "=v"(d) : "v"(a), "v"(b), "v"(c));
    return d;
#endif
}

__device__ __forceinline__ unsigned quant8(float v) {
    float t = (v - QOFF) * QINV + 0.5f;
    t = fminf(fmaxf(t, 0.0f), 255.0f);
    return (unsigned)(int)t;
}

__device__ __forceinline__ unsigned cvt_pk_bf16(float lo, float hi) {
    unsigned r;
    asm("v_cvt_pk_bf16_f32 %0, %1, %2" : "=v"(r) : "v"(lo), "v"(hi));
    return r;
}

__device__ __forceinline__ unsigned short f2bf(float v) {
    return (unsigned short)(cvt_pk_bf16(v, v) & 0xffffu);
}

__device__ __forceinline__ float bf2f(unsigned short u) {
    union { unsigned u; float f; } x; x.u = ((unsigned)u) << 16; return x.f;
}

__device__ __forceinline__ bf16x8 mkbf(unsigned u0, unsigned u1, unsigned u2, unsigned u3) {
    union { unsigned u[4]; bf16x8 v; } x;
    x.u[0] = u0; x.u[1] = u1; x.u[2] = u2; x.u[3] = u3;
    return x.v;
}

__device__ __forceinline__ bf16x8 bfc(uint4 q) {
    union { uint4 q; bf16x8 v; } x; x.q = q; return x.v;
}

// async global->LDS, 16B per lane, dest = wave-uniform base + lane*16
#define GLDS(gsrc, ldst) \
    __builtin_amdgcn_global_load_lds((const __attribute__((address_space(1))) unsigned*)(gsrc), \
                                     (__attribute__((address_space(3))) unsigned*)(ldst), 16, 0, 0)

// ---------------- Kernel A: prep ----------------
// cb<8: q GEMM -> qq8; k quantize -> kq8a (chunks 0,1) + kq8b (chunks 2,3), both PLAIN layout
//        [bh][1024 rows][2 chunks of 16B]. (attn permutes via per-lane GLDS source / direct global)
// cb>=8: v GEMM -> vfrag bf16 B-fragment layout
__global__ __launch_bounds__(256) void prep_kernel(
    const float* __restrict__ x, const float* __restrict__ wq,
    const float* __restrict__ wv, const float* __restrict__ wk,
    unsigned* __restrict__ qq8, uint4* __restrict__ kq8a, uint4* __restrict__ kq8b,
    uint4* __restrict__ vfrag)
{
    __shared__ float xs[64][68];
    __shared__ float ws[64][65];
    __shared__ float vS[64][68];
    const int tid = threadIdx.x;
    const int st = blockIdx.x;
    const int cb = blockIdx.y;
    const int b  = blockIdx.z;
    const bool isQ = (cb < 8);
    const int h = isQ ? cb : (cb - 8);
    const float* W = isQ ? wq : wv;
    const int cBase = h * 64;
    const int bh = b * NHh + h;

#pragma unroll
    for (int i = 0; i < 4; ++i) {
        int f4 = tid + i * 256;
        int r = f4 >> 4, c4 = (f4 & 15) << 2;
        int row = st * 64 + r; if (row >= Tt) row = Tt - 1;
        *(float4*)&xs[r][c4] = *(const float4*)&x[((size_t)b * Tt + row) * 64 + c4];
    }
#pragma unroll
    for (int i = 0; i < 16; ++i) {
        int idx = tid + i * 256;
        int c = idx >> 6, k = idx & 63;
        ws[c][k] = W[(cBase + c) * 65 + k];
    }
    __syncthreads();

    const int rg = tid >> 4, cg = tid & 15;
    const int r0 = rg * 4, c0 = cg * 4;
    float acc[4][4];
#pragma unroll
    for (int j = 0; j < 4; ++j) {
        float bias = W[(cBase + c0 + j) * 65 + 64];
#pragma unroll
        for (int i = 0; i < 4; ++i) acc[i][j] = bias;
    }
    for (int k0 = 0; k0 < 64; k0 += 4) {
        float4 a[4];
#pragma unroll
        for (int i = 0; i < 4; ++i) a[i] = *(const float4*)&xs[r0 + i][k0];
#pragma unroll
        for (int j = 0; j < 4; ++j) {
            float b0 = ws[c0 + j][k0 + 0];
            float b1 = ws[c0 + j][k0 + 1];
            float b2 = ws[c0 + j][k0 + 2];
            float b3 = ws[c0 + j][k0 + 3];
#pragma unroll
            for (int i = 0; i < 4; ++i)
                acc[i][j] += a[i].x * b0 + a[i].y * b1 + a[i].z * b2 + a[i].w * b3;
        }
    }

    if (isQ) {
#pragma unroll
        for (int i = 0; i < 4; ++i) {
            int t = st * 64 + r0 + i;
            unsigned d = 0u;
            if (t < Tt)
                d = quant8(acc[i][0]) | (quant8(acc[i][1]) << 8) |
                    (quant8(acc[i][2]) << 16) | (quant8(acc[i][3]) << 24);
            qq8[((size_t)bh * TPAD + t) * 16 + cg] = d;
        }
        {
            const int r = tid >> 2, c4 = tid & 3;
            const int t = st * 64 + r;
            unsigned kd[4];
            if (t < Tt) {
#pragma unroll
                for (int dw = 0; dw < 4; ++dw) {
                    int w = c4 * 16 + dw * 4;
                    float4 wkv = *(const float4*)&wk[h * 64 + w];
                    kd[dw] = quant8(xs[r][w + 0] * wkv.x) |
                             (quant8(xs[r][w + 1] * wkv.y) << 8) |
                             (quant8(xs[r][w + 2] * wkv.z) << 16) |
                             (quant8(xs[r][w + 3] * wkv.w) << 24);
                }
            } else {
                kd[0] = kd[1] = kd[2] = kd[3] = 0u;
            }
            uint4 v4 = make_uint4(kd[0], kd[1], kd[2], kd[3]);
            if (c4 < 2)
                kq8a[((size_t)bh * TPAD + t) * 2 + c4] = v4;
            else
                kq8b[((size_t)bh * TPAD + t) * 2 + (c4 - 2)] = v4;
        }
    } else {
#pragma unroll
        for (int i = 0; i < 4; ++i) {
            float4 o; o.x = acc[i][0]; o.y = acc[i][1]; o.z = acc[i][2]; o.w = acc[i][3];
            *(float4*)&vS[r0 + i][c0] = o;
        }
        __syncthreads();
#pragma unroll
        for (int e2 = 0; e2 < 2; ++e2) {
            int ent = tid + e2 * 256;
            int kk = ent >> 8, rem = ent & 255, n = rem >> 6, lane = rem & 63;
            int ts = kk * 32 + ((lane >> 4) << 3);
            int w  = n * 16 + (lane & 15);
            unsigned o[4];
#pragma unroll
            for (int pr = 0; pr < 4; ++pr) {
                int t0 = st * 64 + ts + pr * 2;
                float lo = (t0 < Tt)     ? vS[ts + pr * 2][w]     : 0.0f;
                float hi = (t0 + 1 < Tt) ? vS[ts + pr * 2 + 1][w] : 0.0f;
                o[pr] = cvt_pk_bf16(lo, hi);
            }
            vfrag[(((size_t)bh * 16 + st) * 8 + (kk * 4 + n)) * 64 + lane] =
                make_uint4(o[0], o[1], o[2], o[3]);
        }
    }
}

// ---------------- Kernel B: attention, 3-pipe split (LDS + VMEM + VALU) ----------------
// r10 structure (A=2, split-K x2 blocks, 4 waves: rowhalf x tileq) but k is split by chunk:
// chunks 0,1 staged in LDS (2KB/tile; per-lane-source permutation u=kk*64+e*8+g*2+c makes
// read addresses (g*2+c)%8 -> conflict-free); chunks 2,3 read directly global (L2-served,
// group-shared addresses coalesce, immediate-offset loads). LDS-pipe traffic halves vs r10;
// the VMEM pipe (idle except V) absorbs the other half in parallel.
__global__ __launch_bounds__(256) void attn_kernel(
    const unsigned* __restrict__ qq8, const uint4* __restrict__ kq8a,
    const uint4* __restrict__ kq8b, const uint4* __restrict__ vfrag,
    unsigned short* __restrict__ numbf, float* __restrict__ dsums)
{
    __shared__ uint4 smem[1024];       // staging uses first 512 (8KB); reduce reuses all 16KB
    __shared__ float dred[2][2][16];   // [rowhalf][rowset][m]

    const int tid = threadIdx.x;
    const int wv_ = tid >> 6;          // wave 0..3
    const int l   = tid & 63;
    const int g   = l >> 4;            // 0..3
    const int m   = l & 15;
    const int qt  = blockIdx.x;        // 0..15
    const int h   = blockIdx.y;
    const int bz  = blockIdx.z;        // 0..15
    const int b   = bz >> 1;
    const int half = bz & 1;
    const int bh  = b * NHh + h;
    const int rowhalf = wv_ & 1;
    const int tileq   = wv_ >> 1;      // 0..1
    const int rowbase = qt * 64 + rowhalf * 32;
    const int tbase   = half * 8 + tileq * 4;

    // two q rows per lane (16 dw each): rows rowbase+m and rowbase+16+m
    unsigned qa[16], qb[16];
    {
        const uint4* qp = (const uint4*)qq8 + ((size_t)bh * TPAD + rowbase + m) * 4;
        *(uint4*)&qa[0]  = qp[0];  *(uint4*)&qa[4]  = qp[1];
        *(uint4*)&qa[8]  = qp[2];  *(uint4*)&qa[12] = qp[3];
        const uint4* qp2 = qp + 64;
        *(uint4*)&qb[0]  = qp2[0]; *(uint4*)&qb[4]  = qp2[1];
        *(uint4*)&qb[8]  = qp2[2]; *(uint4*)&qb[12] = qp2[3];
    }

    const unsigned* kga = (const unsigned*)kq8a + (size_t)bh * TPAD * 8;  // dwords; row stride 8
    const uint4*    kgb = kq8b + (size_t)bh * TPAD * 2;                   // uint4;  row stride 2
    const uint4*    vg  = vfrag + (size_t)bh * 8192;                      // tile t at +t*512

    // staging lane constants: this lane stages unit u = hu*64 + l of its wave's tile;
    // decode: kk=hu, e=l>>3, gs=(l>>1)&3, c=l&1 -> row_local = hu*32 + gs*8 + e, chunk c
    const int hu = wv_ & 1;
    const int st_row = hu * 32 + (((l >> 1) & 3) << 3) + (l >> 3);
    const int st_off = st_row * 8 + (l & 1) * 4;        // dwords within tile (tile = 64 rows * 8 dw)

    unsigned* kSd = (unsigned*)smem;   // staging region: 4 tile-slots * 512 dwords = 8KB

    // stage k(chunks 0,1) of tile (tbase+I) into slot (BUF*2 + tileq); 1 GLDS per wave
#define STAGEK(I, BUF) \
    GLDS(kga + ((size_t)(tbase + (I)) * 64) * 8 + st_off, \
         kSd + (((BUF) * 2 + tileq) * 512 + hu * 256))

    STAGEK(0, 0);
    __syncthreads();   // drains vmcnt

    f32x4 aca[4], acb[4];
#pragma unroll
    for (int n = 0; n < 4; ++n) { aca[n] = (f32x4){0.f,0.f,0.f,0.f}; acb[n] = aca[n]; }
    float dsum_a = 0.0f, dsum_b = 0.0f;

#pragma unroll 1
    for (int i = 0; i < 4; ++i) {
        const int cur = i & 1;
        const int t = tbase + i;
        const uint4* kb = (const uint4*)(kSd + (cur * 2 + tileq) * 512);  // 128 uint4 tile
        const uint4* vt = vg + (size_t)t * 512 + l;

        if (i < 3) STAGEK(i + 1, cur ^ 1);

#pragma unroll
        for (int kk = 0; kk < 2; ++kk) {
            // V fragments (global; latency hides under SADs)
            uint4 vf0 = vt[(kk * 4 + 0) * 64];
            uint4 vf1 = vt[(kk * 4 + 1) * 64];
            uint4 vf2 = vt[(kk * 4 + 2) * 64];
            uint4 vf3 = vt[(kk * 4 + 3) * 64];

            const uint4* kbl = kb + kk * 64 + g * 2;                       // LDS chunks 0,1
            const uint4* gk  = kgb + ((size_t)t * 64 + kk * 32 + (g << 3)) * 2;  // global chunks 2,3

            const bool maskall = (t == 15) && (kk == 1) && (g >= 1);
            unsigned wa[4], wb[4];
            float pva = 0.f, pvb = 0.f;
#pragma unroll
            for (int e = 0; e < 8; ++e) {
                uint4 c0 = kbl[e * 8];
                uint4 c1 = kbl[e * 8 + 1];
                uint4 c2 = gk[e * 2];
                uint4 c3 = gk[e * 2 + 1];
                const unsigned* k0 = (const unsigned*)&c0;
                const unsigned* k1 = (const unsigned*)&c1;
                const unsigned* k2 = (const unsigned*)&c2;
                const unsigned* k3 = (const unsigned*)&c3;
                unsigned sa0 = 0u, sa1 = 0u, sb0 = 0u, sb1 = 0u;
#pragma unroll
                for (int w = 0; w < 4; ++w) {
                    sa0 = sad_u8(qa[w],      k0[w], sa0);
                    sa1 = sad_u8(qa[4 + w],  k1[w], sa1);
                    sb0 = sad_u8(qb[w],      k0[w], sb0);
                    sb1 = sad_u8(qb[4 + w],  k1[w], sb1);
                }
#pragma unroll
                for (int w = 0; w < 4; ++w) {
                    sa0 = sad_u8(qa[8 + w],  k2[w], sa0);
                    sa1 = sad_u8(qa[12 + w], k3[w], sa1);
                    sb0 = sad_u8(qb[8 + w],  k2[w], sb0);
                    sb1 = sad_u8(qb[12 + w], k3[w], sb1);
                }
                float pea = maskall ? 0.0f : __builtin_amdgcn_exp2f(CQ * (float)(sa0 + sa1));
                float peb = maskall ? 0.0f : __builtin_amdgcn_exp2f(CQ * (float)(sb0 + sb1));
                dsum_a += pea; dsum_b += peb;
                if (e & 1) { wa[e >> 1] = cvt_pk_bf16(pva, pea); wb[e >> 1] = cvt_pk_bf16(pvb, peb); }
                else       { pva = pea; pvb = peb; }
            }
            bf16x8 Aa = mkbf(wa[0], wa[1], wa[2], wa[3]);
            bf16x8 Ab = mkbf(wb[0], wb[1], wb[2], wb[3]);

            aca[0] = __builtin_amdgcn_mfma_f32_16x16x32_bf16(Aa, bfc(vf0), aca[0], 0, 0, 0);
            acb[0] = __builtin_amdgcn_mfma_f32_16x16x32_bf16(Ab, bfc(vf0), acb[0], 0, 0, 0);
            aca[1] = __builtin_amdgcn_mfma_f32_16x16x32_bf16(Aa, bfc(vf1), aca[1], 0, 0, 0);
            acb[1] = __builtin_amdgcn_mfma_f32_16x16x32_bf16(Ab, bfc(vf1), acb[1], 0, 0, 0);
            aca[2] = __builtin_amdgcn_mfma_f32_16x16x32_bf16(Aa, bfc(vf2), aca[2], 0, 0, 0);
            acb[2] = __builtin_amdgcn_mfma_f32_16x16x32_bf16(Ab, bfc(vf2), acb[2], 0, 0, 0);
            aca[3] = __builtin_amdgcn_mfma_f32_16x16x32_bf16(Aa, bfc(vf3), aca[3], 0, 0, 0);
            acb[3] = __builtin_amdgcn_mfma_f32_16x16x32_bf16(Ab, bfc(vf3), acb[3], 0, 0, 0);
        }

        __syncthreads();   // publishes next buffer; drains stages
    }
#undef STAGEK

    // intra-wave denominator reduce over the 4 lane-groups sharing m
    dsum_a += __shfl_xor(dsum_a, 16);
    dsum_a += __shfl_xor(dsum_a, 32);
    dsum_b += __shfl_xor(dsum_b, 16);
    dsum_b += __shfl_xor(dsum_b, 32);

    // cross-wave pair reduce (tileq 1 -> tileq 0) via LDS (reuses full 16KB smem)
    f32x4* red = (f32x4*)smem;
    if (tileq == 1) {
#pragma unroll
        for (int n = 0; n < 4; ++n) {
            red[(((rowhalf * 2 + 0) * 4) + n) * 64 + l] = aca[n];
            red[(((rowhalf * 2 + 1) * 4) + n) * 64 + l] = acb[n];
        }
        if (l < 16) { dred[rowhalf][0][l] = dsum_a; dred[rowhalf][1][l] = dsum_b; }
    }
    __syncthreads();
    if (tileq == 0) {
#pragma unroll
        for (int n = 0; n < 4; ++n) {
            f32x4 ra = red[(((rowhalf * 2 + 0) * 4) + n) * 64 + l];
            f32x4 rb = red[(((rowhalf * 2 + 1) * 4) + n) * 64 + l];
#pragma unroll
            for (int j = 0; j < 4; ++j) { aca[n][j] += ra[j]; acb[n][j] += rb[j]; }
        }
        const float dta = dsum_a + dred[rowhalf][0][m];
        const float dtb = dsum_b + dred[rowhalf][1][m];

        // raw bf16 numerators: [(b*Tt+row)*16 + h*2+half][64]
#pragma unroll
        for (int j = 0; j < 4; ++j) {
            int row_a = rowbase + g * 4 + j;
            int row_b = rowbase + 16 + g * 4 + j;
            if (row_a < Tt) {
                unsigned short* o = numbf + (((size_t)(b * Tt + row_a) * 16) + h * 2 + half) * 64 + m;
                o[0]  = f2bf(aca[0][j]);
                o[16] = f2bf(aca[1][j]);
                o[32] = f2bf(aca[2][j]);
                o[48] = f2bf(aca[3][j]);
            }
            if (row_b < Tt) {
                unsigned short* o = numbf + (((size_t)(b * Tt + row_b) * 16) + h * 2 + half) * 64 + m;
                o[0]  = f2bf(acb[0][j]);
                o[16] = f2bf(acb[1][j]);
                o[32] = f2bf(acb[2][j]);
                o[48] = f2bf(acb[3][j]);
            }
        }
        if (l < 16) {
            int ra = rowbase + m, rb = rowbase + 16 + m;
            if (ra < Tt) dsums[(((size_t)(b * Tt + ra) * 8) + h) * 2 + half] = dta;
            if (rb < Tt) dsums[(((size_t)(b * Tt + rb) * 8) + h) * 2 + half] = dtb;
        }
    }
}

// ---------------- Kernel C: normalize + half/head-sum + ReLU + wf proj + residual ----
__global__ __launch_bounds__(256) void finalize_kernel(
    const float* __restrict__ x, const float* __restrict__ wf,
    const unsigned short* __restrict__ numbf, const float* __restrict__ dsums,
    float* __restrict__ out)
{
    __shared__ float wfs[64][65];
    __shared__ float osh[4][64];
    const int tid = threadIdx.x;
    for (int i = tid; i < 64 * 65; i += 256) wfs[i / 65][i % 65] = wf[i];
    const int wave = tid >> 6, lane = tid & 63;
    const int token = blockIdx.x * 4 + wave;   // 0..7999

    const float dsv = dsums[(size_t)token * 16 + (lane & 15)];
    const unsigned short* np = numbf + (size_t)token * 1024;
    float o = 0.f;
#pragma unroll
    for (int hh = 0; hh < 8; ++hh) {
        float den = 1.0f + __shfl(dsv, 2 * hh) + __shfl(dsv, 2 * hh + 1);
        float inv = 1.0f / den;
        float a0 = bf2f(np[(2 * hh) * 64 + lane]);
        float a1 = bf2f(np[(2 * hh + 1) * 64 + lane]);
        o += (a0 + a1) * inv;
    }
    o = fmaxf(o, 0.f);
    osh[wave][lane] = o;
    __syncthreads();
    float acc = wfs[lane][64];    // bias
#pragma unroll 8
    for (int w = 0; w < 64; ++w) acc += wfs[lane][w] * osh[wave][w];
    out[(size_t)token * Dd + lane] = x[(size_t)token * Dd + lane] + acc;
}

extern "C" void kernel_launch(void* const* d_in, const int* in_sizes, int n_in,
                              void* d_out, int out_size, void* d_ws, size_t ws_size,
                              hipStream_t stream)
{
    const float* x  = (const float*)d_in[0];
    const float* wq = (const float*)d_in[1];
    const float* wv = (const float*)d_in[2];
    const float* wk = (const float*)d_in[3];
    const float* wf = (const float*)d_in[4];
    float* out = (float*)d_out;

    char* base = (char*)d_ws;
    unsigned short* numbf = (unsigned short*)base;                    // 16,384,000 B
    float*    dsums = (float*)(base + 16384000);                      //    512,000 B
    unsigned* qq8   = (unsigned*)(base + 16896000);                   //  4,194,304 B
    uint4*    kq8a  = (uint4*)(base + 16896000 + 4194304);            //  2,097,152 B
    uint4*    kq8b  = (uint4*)(base + 16896000 + 4194304 + 2097152);  //  2,097,152 B
    uint4*    vfrag = (uint4*)(base + 16896000 + 2 * 4194304);        //  8,388,608 B

    prep_kernel<<<dim3(16, 16, Bb), 256, 0, stream>>>(x, wq, wv, wk, qq8, kq8a, kq8b, vfrag);
    attn_kernel<<<dim3(16, NHh, 2 * Bb), 256, 0, stream>>>(qq8, kq8a, kq8b, vfrag, numbf, dsums);
    finalize_kernel<<<2000, 256, 0, stream>>>(x, wf, numbf, dsums, out);
}